// Round 6
// baseline (1136.039 us; speedup 1.0000x reference)
//
#include <hip/hip_runtime.h>

#define CDIM 64
#define HDIM 256
#define WDIM 256
#define HWSZ (HDIM * WDIM)
#define GNUM 8

typedef _Float16 f16;
typedef f16  f16x8  __attribute__((ext_vector_type(8)));
typedef float f32x4 __attribute__((ext_vector_type(4)));

static __device__ __forceinline__ ushort f16bits(float v) {
    f16 h = (f16)v;
    return __builtin_bit_cast(ushort, h);
}

// ---------------------------------------------------------------------------
// Repack OIHW f32 -> [tap][oc][ic] f16 (ic contiguous -> 16B fragment chunks).
// ---------------------------------------------------------------------------
__global__ __launch_bounds__(256) void repack_wf16(const float* __restrict__ w,
                                                   ushort* __restrict__ wt, int TAPS) {
    int idx = blockIdx.x * 256 + threadIdx.x;
    int total = 64 * 64 * TAPS;
    if (idx >= total) return;
    int tap = idx / 4096;
    int rem = idx - tap * 4096;
    int oc = rem >> 6, ic = rem & 63;
    wt[idx] = f16bits(w[(oc * 64 + ic) * TAPS + tap]);
}

// Repack OIHW f32 -> [ic][OC] f32 (1x1 convs; uniform scalar loads).
__global__ __launch_bounds__(256) void repack_oihw(const float* __restrict__ w,
                                                   float* __restrict__ wt,
                                                   int OC, int IC) {
    int idx = blockIdx.x * 256 + threadIdx.x;
    if (idx >= OC * IC) return;
    int oc = idx / IC, ic = idx - oc * IC;
    wt[ic * OC + oc] = w[idx];
}

// ---------------------------------------------------------------------------
// Implicit-GEMM conv via mfma_f32_16x16x32_f16.
//   D[pix][oc] = sum_{tap,ic} A[pix(shifted)][ic] * W[tap][oc][ic]
// Block: 256 thr = 4 waves, tile 32x x 8y pixels, all 64 oc.
// A staged once in LDS as [pix][64ch] f16 (16B chunks XOR-swizzled by x&7);
// B-fragments loaded DIRECTLY from global (weights are L2-resident; removes
// all per-tap staging barriers -> K-loop is barrier-free).
// Fragment layout (16x16x32 f16): A: lane = [m=lane&15][k=(lane>>4)*8+j];
// B: [n=lane&15][k=(lane>>4)*8+j]; D: [m=(lane>>4)*4+r][n=lane&15].
// ---------------------------------------------------------------------------
template <int KS, bool IN_F32_NCHW, bool PRELU, bool F32OUT>
__global__ __launch_bounds__(256, 2) void conv_mfma(
        const void* __restrict__ inp,
        const ushort* __restrict__ wt,     // f16 [tap][64][64]
        const float* __restrict__ bias,
        const float* __restrict__ alpha,
        const float* __restrict__ resid,   // f32 NCHW (F32OUT only)
        void* __restrict__ outp) {
    constexpr int H  = KS / 2;
    constexpr int TX = 32, TY = 8;
    constexpr int IX = TX + 2 * H, IY = TY + 2 * H;
    constexpr int NP = IX * IY;

    __shared__ __align__(16) ushort sX[NP * 64];

    const int b    = blockIdx.z;
    const int bx   = blockIdx.x * TX;
    const int by   = blockIdx.y * TY;
    const int tid  = threadIdx.x;
    const int lane = tid & 63;
    const int wv   = tid >> 6;
    const int x0w  = (wv & 1) * 16;
    const int y0w  = (wv >> 1) * 4;
    const int lr   = lane & 15;
    const int hi   = lane >> 4;

    // ---- stage input tile (once) ----
    if constexpr (IN_F32_NCHW) {
        const float* inf = (const float*)inp + (size_t)b * CDIM * HWSZ;
        for (int i = tid; i < CDIM * NP; i += 256) {
            int ch = i / NP, p = i - ch * NP;
            int iy = p / IX, ix = p - iy * IX;
            int gy = by - H + iy, gx = bx - H + ix;
            float v = 0.f;
            if (gy >= 0 && gy < HDIM && gx >= 0 && gx < WDIM)
                v = inf[ch * HWSZ + gy * WDIM + gx];
            int chunk = (ch >> 3) ^ (ix & 7);
            sX[p * 64 + chunk * 8 + (ch & 7)] = f16bits(v);
        }
    } else {
        const ushort* inh = (const ushort*)inp + (size_t)b * HWSZ * 64;
        for (int i = tid; i < NP * 8; i += 256) {
            int p = i >> 3, chunk = i & 7;
            int iy = p / IX, ix = p - iy * IX;
            int gy = by - H + iy, gx = bx - H + ix;
            uint4 v = make_uint4(0u, 0u, 0u, 0u);
            if (gy >= 0 && gy < HDIM && gx >= 0 && gx < WDIM)
                v = *(const uint4*)(inh + ((size_t)(gy * WDIM + gx)) * 64 + chunk * 8);
            *(uint4*)((char*)sX + p * 128 + ((chunk ^ (ix & 7)) << 4)) = v;
        }
    }
    __syncthreads();

    f32x4 acc[4][4] = {};

    for (int tap = 0; tap < KS * KS; ++tap) {
        const int dy = tap / KS, dx = tap - dy * KS;
        // B-fragments for both K-halves straight from global (L1/L2-hit)
        f16x8 bfr[2][4];
#pragma unroll
        for (int ks = 0; ks < 2; ++ks)
#pragma unroll
            for (int nt = 0; nt < 4; ++nt) {
                const ushort* wp = wt + (size_t)tap * 4096 + (nt * 16 + lr) * 64
                                      + ks * 32 + hi * 8;
                bfr[ks][nt] = *(const f16x8*)wp;
            }
#pragma unroll
        for (int ks = 0; ks < 2; ++ks) {
            f16x8 afr[4];
#pragma unroll
            for (int mt = 0; mt < 4; ++mt) {
                int iy = y0w + mt + dy;
                int ix = x0w + dx + lr;
                int chunk = (ks * 4 + hi) ^ (ix & 7);
                afr[mt] = *(const f16x8*)((const char*)sX + (iy * IX + ix) * 128 + (chunk << 4));
            }
#pragma unroll
            for (int mt = 0; mt < 4; ++mt)
#pragma unroll
                for (int nt = 0; nt < 4; ++nt)
                    acc[mt][nt] = __builtin_amdgcn_mfma_f32_16x16x32_f16(
                        afr[mt], bfr[ks][nt], acc[mt][nt], 0, 0, 0);
        }
    }

    // ---- epilogue ----
    const float al = PRELU ? alpha[0] : 0.f;
#pragma unroll
    for (int nt = 0; nt < 4; ++nt) {
        const int oc = nt * 16 + lr;
        const float bs = bias[oc];
#pragma unroll
        for (int mt = 0; mt < 4; ++mt) {
            const int gy = by + y0w + mt;
            const int gxb = bx + x0w + hi * 4;
            if constexpr (!F32OUT) {
                ushort* o = (ushort*)outp + (size_t)b * HWSZ * 64;
#pragma unroll
                for (int r = 0; r < 4; ++r) {
                    float v = acc[mt][nt][r] + bs;
                    if constexpr (PRELU) v = (v >= 0.f) ? v : al * v;
                    o[((size_t)(gy * WDIM + gxb + r)) * 64 + oc] = f16bits(v);
                }
            } else {
                float* o = (float*)outp;
                size_t base = ((size_t)(b * CDIM + oc)) * HWSZ + gy * WDIM + gxb;
                float4 sv = *(const float4*)(resid + base);
                float4 ov;
                ov.x = acc[mt][nt][0] + bs + sv.x;
                ov.y = acc[mt][nt][1] + bs + sv.y;
                ov.z = acc[mt][nt][2] + bs + sv.z;
                ov.w = acc[mt][nt][3] + bs + sv.w;
                *(float4*)(o + base) = ov;
            }
        }
    }
}

// ---------------------------------------------------------------------------
// Fused bilateral kernel, 2 groups per block (grid z = batch*4 + group-pair).
// r2/g2 (f16 NHWC) loaded ONCE into registers, reused for both groups.
// Per-group: stage 8 src channels (20x20 f32) in LDS, compute kt/kg via
// uniform-weight FMA, product, 25-tap apply, immediate f16x8 store.
// ---------------------------------------------------------------------------
__global__ __launch_bounds__(256, 4) void jbf_fused(const f16* __restrict__ r2,
                                                    const f16* __restrict__ g2,
                                                    const float* __restrict__ src,
                                                    const float* __restrict__ wt3t,
                                                    const float* __restrict__ tb3,
                                                    const float* __restrict__ wt3g,
                                                    const float* __restrict__ gb3,
                                                    ushort* __restrict__ out) {
    constexpr int IT = 20;  // 16 + 4
    __shared__ float sSrc[8 * IT * IT];

    const int b   = blockIdx.z >> 2;
    const int g0  = (blockIdx.z & 3) * 2;
    const int tx0 = blockIdx.x * 16;
    const int ty0 = blockIdx.y * 16;
    const int tid = threadIdx.x;
    const int lx  = tid & 15;
    const int ly  = tid >> 4;

    const size_t pix = (size_t)(ty0 + ly) * WDIM + (tx0 + lx);
    const f16*   r2b = r2 + (size_t)b * HWSZ * 64;
    const f16*   g2b = g2 + (size_t)b * HWSZ * 64;
    const float* srcb = src + (size_t)b * CDIM * HWSZ;
    ushort* ob = out + (size_t)b * HWSZ * 64;

    // load the 64-channel r2/g2 rows once (32 VGPRs)
    f16x8 rv[8], gv[8];
#pragma unroll
    for (int icv = 0; icv < 8; ++icv) {
        rv[icv] = *(const f16x8*)(r2b + pix * 64 + icv * 8);
        gv[icv] = *(const f16x8*)(g2b + pix * 64 + icv * 8);
    }

    for (int gi = 0; gi < 2; ++gi) {
        const int g = g0 + gi;
        __syncthreads();
        for (int i = tid; i < 8 * IT * IT; i += 256) {
            int c   = i / (IT * IT);
            int rem = i - c * (IT * IT);
            int yy  = rem / IT;
            int xx  = rem - yy * IT;
            int gy  = ty0 - 2 + yy;
            int gx  = tx0 - 2 + xx;
            float v = 0.f;
            if (gy >= 0 && gy < HDIM && gx >= 0 && gx < WDIM)
                v = srcb[(size_t)(g * 8 + c) * HWSZ + gy * WDIM + gx];
            sSrc[i] = v;
        }
        __syncthreads();

        float kt[25], kg[25];
#pragma unroll
        for (int t = 0; t < 25; ++t) {
            kt[t] = tb3[g * 25 + t];
            kg[t] = gb3[g * 25 + t];
        }
        for (int icv = 0; icv < 8; ++icv) {
#pragma unroll
            for (int j = 0; j < 8; ++j) {
                float vr = (float)rv[icv][j];
                float vg = (float)gv[icv][j];
                const int ic = icv * 8 + j;
                const float* wpt = wt3t + ic * 200 + g * 25;
                const float* wpg = wt3g + ic * 200 + g * 25;
#pragma unroll
                for (int t = 0; t < 25; ++t) {
                    kt[t] = fmaf(vr, wpt[t], kt[t]);
                    kg[t] = fmaf(vg, wpg[t], kg[t]);
                }
            }
        }
#pragma unroll
        for (int t = 0; t < 25; ++t) kt[t] *= kg[t];

        f16x8 h;
#pragma unroll
        for (int c = 0; c < 8; ++c) {
            float a = 0.f;
#pragma unroll
            for (int t = 0; t < 25; ++t) {
                int dy = t / 5, dx = t - dy * 5;
                a = fmaf(kt[t], sSrc[c * IT * IT + (ly + dy) * IT + (lx + dx)], a);
            }
            h[c] = (f16)a;
        }
        *(uint4*)(ob + pix * 64 + g * 8) = __builtin_bit_cast(uint4, h);
    }
}

// ---------------------------------------------------------------------------
extern "C" void kernel_launch(void* const* d_in, const int* in_sizes, int n_in,
                              void* d_out, int out_size, void* d_ws, size_t ws_size,
                              hipStream_t stream) {
    const float* source   = (const float*)d_in[0];
    const float* guidance = (const float*)d_in[1];
    const float* t_w1 = (const float*)d_in[2];
    const float* t_b1 = (const float*)d_in[3];
    const float* t_a1 = (const float*)d_in[4];
    const float* t_w2 = (const float*)d_in[5];
    const float* t_b2 = (const float*)d_in[6];
    const float* t_a2 = (const float*)d_in[7];
    const float* t_w3 = (const float*)d_in[8];
    const float* t_b3 = (const float*)d_in[9];
    const float* g_w1 = (const float*)d_in[10];
    const float* g_b1 = (const float*)d_in[11];
    const float* g_a1 = (const float*)d_in[12];
    const float* g_w2 = (const float*)d_in[13];
    const float* g_b2 = (const float*)d_in[14];
    const float* g_a2 = (const float*)d_in[15];
    const float* g_w3 = (const float*)d_in[16];
    const float* g_b3 = (const float*)d_in[17];
    const float* j_w1 = (const float*)d_in[18];
    const float* j_b1 = (const float*)d_in[19];
    const float* j_a1 = (const float*)d_in[20];
    const float* j_w2 = (const float*)d_in[21];
    const float* j_b2 = (const float*)d_in[22];

    // workspace: two f16 NHWC activation planes + repacked weights.
    // d_out doubles as the g2 f16 plane before the final f32 write.
    const size_t planeH = (size_t)2 * HWSZ * 64;
    ushort* bufA  = (ushort*)d_ws;
    ushort* bufB  = bufA + planeH;
    ushort* wt_t1 = bufB + planeH;
    ushort* wt_t2 = wt_t1 + 102400;
    ushort* wt_g1 = wt_t2 + 102400;
    ushort* wt_g2 = wt_g1 + 102400;
    ushort* wt_j1 = wt_g2 + 102400;
    ushort* wt_j2 = wt_j1 + 36864;
    float*  wt_t3 = (float*)(wt_j2 + 36864);
    float*  wt_g3 = wt_t3 + 12800;
    ushort* bufC  = (ushort*)d_out;

    repack_wf16<<<(64 * 64 * 25 + 255) / 256, 256, 0, stream>>>(t_w1, wt_t1, 25);
    repack_wf16<<<(64 * 64 * 25 + 255) / 256, 256, 0, stream>>>(t_w2, wt_t2, 25);
    repack_wf16<<<(64 * 64 * 25 + 255) / 256, 256, 0, stream>>>(g_w1, wt_g1, 25);
    repack_wf16<<<(64 * 64 * 25 + 255) / 256, 256, 0, stream>>>(g_w2, wt_g2, 25);
    repack_wf16<<<(64 * 64 * 9 + 255) / 256, 256, 0, stream>>>(j_w1, wt_j1, 9);
    repack_wf16<<<(64 * 64 * 9 + 255) / 256, 256, 0, stream>>>(j_w2, wt_j2, 9);
    repack_oihw<<<(200 * 64 + 255) / 256, 256, 0, stream>>>(t_w3, wt_t3, 200, 64);
    repack_oihw<<<(200 * 64 + 255) / 256, 256, 0, stream>>>(g_w3, wt_g3, 200, 64);

    dim3 cgrid(WDIM / 32, HDIM / 8, 2);
    dim3 blk(256);

    conv_mfma<5, true,  true,  false><<<cgrid, blk, 0, stream>>>(source,   wt_t1, t_b1, t_a1, nullptr, bufA);
    conv_mfma<5, false, true,  false><<<cgrid, blk, 0, stream>>>(bufA,     wt_t2, t_b2, t_a2, nullptr, bufB);
    conv_mfma<5, true,  true,  false><<<cgrid, blk, 0, stream>>>(guidance, wt_g1, g_b1, g_a1, nullptr, bufA);
    conv_mfma<5, false, true,  false><<<cgrid, blk, 0, stream>>>(bufA,     wt_g2, g_b2, g_a2, nullptr, bufC);

    dim3 jgrid(WDIM / 16, HDIM / 16, 8);  // z = batch*4 + group-pair
    jbf_fused<<<jgrid, blk, 0, stream>>>((const f16*)bufB, (const f16*)bufC, source,
                                         wt_t3, t_b3, wt_g3, g_b3, bufA);

    conv_mfma<3, false, true,  false><<<cgrid, blk, 0, stream>>>(bufA, wt_j1, j_b1, j_a1, nullptr, bufB);
    conv_mfma<3, false, false, true ><<<cgrid, blk, 0, stream>>>(bufB, wt_j2, j_b2, nullptr, source, d_out);
}

// Round 7
// 649.491 us; speedup vs baseline: 1.7491x; 1.7491x over previous
//
#include <hip/hip_runtime.h>

#define CDIM 64
#define HDIM 256
#define WDIM 256
#define HWSZ (HDIM * WDIM)
#define GNUM 8

typedef _Float16 f16;
typedef f16  f16x8  __attribute__((ext_vector_type(8)));
typedef float f32x4 __attribute__((ext_vector_type(4)));

static __device__ __forceinline__ ushort f16bits(float v) {
    f16 h = (f16)v;
    return __builtin_bit_cast(ushort, h);
}

// ---------------------------------------------------------------------------
// Repack OIHW f32 -> [tap][oc][ic] f16 (ic contiguous -> 16B fragment chunks).
// ---------------------------------------------------------------------------
__global__ __launch_bounds__(256) void repack_wf16(const float* __restrict__ w,
                                                   ushort* __restrict__ wt, int TAPS) {
    int idx = blockIdx.x * 256 + threadIdx.x;
    int total = 64 * 64 * TAPS;
    if (idx >= total) return;
    int tap = idx / 4096;
    int rem = idx - tap * 4096;
    int oc = rem >> 6, ic = rem & 63;
    wt[idx] = f16bits(w[(oc * 64 + ic) * TAPS + tap]);
}

// Cast 1x1 weights (200,64) OIHW f32 -> [208][64] f16, zero-padded rows.
__global__ __launch_bounds__(256) void cast_w3(const float* __restrict__ w,
                                               ushort* __restrict__ wt) {
    int idx = blockIdx.x * 256 + threadIdx.x;
    if (idx >= 208 * 64) return;
    int oc = idx >> 6;
    wt[idx] = (oc < 200) ? f16bits(w[idx]) : (ushort)0;
}

// ---------------------------------------------------------------------------
// Implicit-GEMM conv via mfma_f32_16x16x32_f16 (validated rounds 3/6).
// Block: 256 thr = 4 waves, tile 32x x 8y pixels, all 64 oc.
// A staged once in LDS (XOR-swizzled 16B chunks); B-fragments direct from
// global (L2-resident weights) -> barrier-free K-loop.
// ---------------------------------------------------------------------------
template <int KS, bool IN_F32_NCHW, bool PRELU, bool F32OUT>
__global__ __launch_bounds__(256, 2) void conv_mfma(
        const void* __restrict__ inp,
        const ushort* __restrict__ wt,     // f16 [tap][64][64]
        const float* __restrict__ bias,
        const float* __restrict__ alpha,
        const float* __restrict__ resid,   // f32 NCHW (F32OUT only)
        void* __restrict__ outp) {
    constexpr int H  = KS / 2;
    constexpr int TX = 32, TY = 8;
    constexpr int IX = TX + 2 * H, IY = TY + 2 * H;
    constexpr int NP = IX * IY;

    __shared__ __align__(16) ushort sX[NP * 64];

    const int b    = blockIdx.z;
    const int bx   = blockIdx.x * TX;
    const int by   = blockIdx.y * TY;
    const int tid  = threadIdx.x;
    const int lane = tid & 63;
    const int wv   = tid >> 6;
    const int x0w  = (wv & 1) * 16;
    const int y0w  = (wv >> 1) * 4;
    const int lr   = lane & 15;
    const int hi   = lane >> 4;

    if constexpr (IN_F32_NCHW) {
        const float* inf = (const float*)inp + (size_t)b * CDIM * HWSZ;
        for (int i = tid; i < CDIM * NP; i += 256) {
            int ch = i / NP, p = i - ch * NP;
            int iy = p / IX, ix = p - iy * IX;
            int gy = by - H + iy, gx = bx - H + ix;
            float v = 0.f;
            if (gy >= 0 && gy < HDIM && gx >= 0 && gx < WDIM)
                v = inf[ch * HWSZ + gy * WDIM + gx];
            int chunk = (ch >> 3) ^ (ix & 7);
            sX[p * 64 + chunk * 8 + (ch & 7)] = f16bits(v);
        }
    } else {
        const ushort* inh = (const ushort*)inp + (size_t)b * HWSZ * 64;
        for (int i = tid; i < NP * 8; i += 256) {
            int p = i >> 3, chunk = i & 7;
            int iy = p / IX, ix = p - iy * IX;
            int gy = by - H + iy, gx = bx - H + ix;
            uint4 v = make_uint4(0u, 0u, 0u, 0u);
            if (gy >= 0 && gy < HDIM && gx >= 0 && gx < WDIM)
                v = *(const uint4*)(inh + ((size_t)(gy * WDIM + gx)) * 64 + chunk * 8);
            *(uint4*)((char*)sX + p * 128 + ((chunk ^ (ix & 7)) << 4)) = v;
        }
    }
    __syncthreads();

    f32x4 acc[4][4] = {};

    for (int tap = 0; tap < KS * KS; ++tap) {
        const int dy = tap / KS, dx = tap - dy * KS;
        f16x8 bfr[2][4];
#pragma unroll
        for (int ks = 0; ks < 2; ++ks)
#pragma unroll
            for (int nt = 0; nt < 4; ++nt) {
                const ushort* wp = wt + (size_t)tap * 4096 + (nt * 16 + lr) * 64
                                      + ks * 32 + hi * 8;
                bfr[ks][nt] = *(const f16x8*)wp;
            }
#pragma unroll
        for (int ks = 0; ks < 2; ++ks) {
            f16x8 afr[4];
#pragma unroll
            for (int mt = 0; mt < 4; ++mt) {
                int iy = y0w + mt + dy;
                int ix = x0w + dx + lr;
                int chunk = (ks * 4 + hi) ^ (ix & 7);
                afr[mt] = *(const f16x8*)((const char*)sX + (iy * IX + ix) * 128 + (chunk << 4));
            }
#pragma unroll
            for (int mt = 0; mt < 4; ++mt)
#pragma unroll
                for (int nt = 0; nt < 4; ++nt)
                    acc[mt][nt] = __builtin_amdgcn_mfma_f32_16x16x32_f16(
                        afr[mt], bfr[ks][nt], acc[mt][nt], 0, 0, 0);
        }
    }

    const float al = PRELU ? alpha[0] : 0.f;
#pragma unroll
    for (int nt = 0; nt < 4; ++nt) {
        const int oc = nt * 16 + lr;
        const float bs = bias[oc];
#pragma unroll
        for (int mt = 0; mt < 4; ++mt) {
            const int gy = by + y0w + mt;
            const int gxb = bx + x0w + hi * 4;
            if constexpr (!F32OUT) {
                ushort* o = (ushort*)outp + (size_t)b * HWSZ * 64;
#pragma unroll
                for (int r = 0; r < 4; ++r) {
                    float v = acc[mt][nt][r] + bs;
                    if constexpr (PRELU) v = (v >= 0.f) ? v : al * v;
                    o[((size_t)(gy * WDIM + gxb + r)) * 64 + oc] = f16bits(v);
                }
            } else {
                float* o = (float*)outp;
                size_t base = ((size_t)(b * CDIM + oc)) * HWSZ + gy * WDIM + gxb;
                float4 sv = *(const float4*)(resid + base);
                float4 ov;
                ov.x = acc[mt][nt][0] + bs + sv.x;
                ov.y = acc[mt][nt][1] + bs + sv.y;
                ov.z = acc[mt][nt][2] + bs + sv.z;
                ov.w = acc[mt][nt][3] + bs + sv.w;
                *(float4*)(o + base) = ov;
            }
        }
    }
}

// ---------------------------------------------------------------------------
// ker = (r2 . W3t + tb3) * (g2 . W3g + gb3)  per batch, via MFMA.
// M = pixels, N = 208 (200 used), K = 64. A-fragments read DIRECTLY from the
// NHWC f16 activations (pixel row == one K=64 fragment row, no LDS).
// Output: ker f16 [65536][200].
// ---------------------------------------------------------------------------
__global__ __launch_bounds__(256, 2) void ker_mfma(
        const ushort* __restrict__ r2,   // [65536][64] f16 (batch slice)
        const ushort* __restrict__ g2,
        const ushort* __restrict__ w3t,  // [208][64] f16, zero-padded
        const float* __restrict__ tb3,   // [200]
        const ushort* __restrict__ w3g,
        const float* __restrict__ gb3,
        ushort* __restrict__ ker) {      // [65536][200] f16
    const int tid  = threadIdx.x;
    const int lane = tid & 63;
    const int wv   = tid >> 6;
    const int lr   = lane & 15;
    const int hi   = lane >> 4;
    const int pixbase = blockIdx.x * 64 + wv * 16;

    f32x4 accr[13] = {}, accg[13] = {};
    const ushort* arb = r2 + (size_t)(pixbase + lr) * 64;
    const ushort* agb = g2 + (size_t)(pixbase + lr) * 64;

#pragma unroll
    for (int ks = 0; ks < 2; ++ks) {
        f16x8 ar = *(const f16x8*)(arb + ks * 32 + hi * 8);
        f16x8 ag = *(const f16x8*)(agb + ks * 32 + hi * 8);
#pragma unroll
        for (int nt = 0; nt < 13; ++nt) {
            f16x8 bt = *(const f16x8*)(w3t + (nt * 16 + lr) * 64 + ks * 32 + hi * 8);
            f16x8 bg = *(const f16x8*)(w3g + (nt * 16 + lr) * 64 + ks * 32 + hi * 8);
            accr[nt] = __builtin_amdgcn_mfma_f32_16x16x32_f16(ar, bt, accr[nt], 0, 0, 0);
            accg[nt] = __builtin_amdgcn_mfma_f32_16x16x32_f16(ag, bg, accg[nt], 0, 0, 0);
        }
    }

#pragma unroll
    for (int nt = 0; nt < 13; ++nt) {
        const int oc = nt * 16 + lr;
        const bool ok = (oc < 200);
        const float bt = ok ? tb3[oc] : 0.f;
        const float bg = ok ? gb3[oc] : 0.f;
#pragma unroll
        for (int r = 0; r < 4; ++r) {
            const int p = pixbase + hi * 4 + r;
            float kv = (accr[nt][r] + bt) * (accg[nt][r] + bg);
            if (ok) ker[(size_t)p * 200 + oc] = f16bits(kv);
        }
    }
}

// ---------------------------------------------------------------------------
// 25-tap grouped apply: out[pix][g*8+c] = sum_t ker[pix][g*25+t]*patch(c,t).
// Block = 16x16 pixels, 4 groups per block (grid z = group-quad).
// Src staged pixel-major [20][20][8ch] f32 -> 2 x ds_read_b128 per tap.
// ---------------------------------------------------------------------------
__global__ __launch_bounds__(256) void jbf_apply(
        const ushort* __restrict__ ker,  // [65536][200] f16
        const float* __restrict__ src,   // f32 NCHW batch slice
        ushort* __restrict__ out) {      // f16 NHWC batch slice
    __shared__ __align__(16) float sSrc[20 * 20 * 8];

    const int g0  = blockIdx.z * 4;
    const int tx0 = blockIdx.x * 16;
    const int ty0 = blockIdx.y * 16;
    const int tid = threadIdx.x;
    const int lx  = tid & 15;
    const int ly  = tid >> 4;
    const int pix = (ty0 + ly) * WDIM + (tx0 + lx);

    for (int gi = 0; gi < 4; ++gi) {
        const int g = g0 + gi;
        __syncthreads();
        for (int i = tid; i < 3200; i += 256) {
            int c   = i / 400;
            int rem = i - c * 400;
            int yy  = rem / 20, xx = rem - yy * 20;
            int gy  = ty0 - 2 + yy, gx = tx0 - 2 + xx;
            float v = 0.f;
            if (gy >= 0 && gy < HDIM && gx >= 0 && gx < WDIM)
                v = src[(size_t)(g * 8 + c) * HWSZ + gy * WDIM + gx];
            sSrc[(yy * 20 + xx) * 8 + c] = v;
        }
        __syncthreads();

        float kt[25];
        const ushort* kp = ker + (size_t)pix * 200 + g * 25;
#pragma unroll
        for (int t = 0; t < 25; ++t)
            kt[t] = (float)(*(const f16*)(kp + t));

        float a8[8] = {};
#pragma unroll
        for (int t = 0; t < 25; ++t) {
            const int dy = t / 5, dx = t - dy * 5;
            const float* sp = &sSrc[((ly + dy) * 20 + (lx + dx)) * 8];
            f32x4 v0 = *(const f32x4*)sp;
            f32x4 v1 = *(const f32x4*)(sp + 4);
#pragma unroll
            for (int c = 0; c < 4; ++c) {
                a8[c]     = fmaf(kt[t], v0[c], a8[c]);
                a8[c + 4] = fmaf(kt[t], v1[c], a8[c + 4]);
            }
        }

        f16x8 h;
#pragma unroll
        for (int c = 0; c < 8; ++c) h[c] = (f16)a8[c];
        *(uint4*)(out + (size_t)pix * 64 + g * 8) = __builtin_bit_cast(uint4, h);
    }
}

// ---------------------------------------------------------------------------
extern "C" void kernel_launch(void* const* d_in, const int* in_sizes, int n_in,
                              void* d_out, int out_size, void* d_ws, size_t ws_size,
                              hipStream_t stream) {
    const float* source   = (const float*)d_in[0];
    const float* guidance = (const float*)d_in[1];
    const float* t_w1 = (const float*)d_in[2];
    const float* t_b1 = (const float*)d_in[3];
    const float* t_a1 = (const float*)d_in[4];
    const float* t_w2 = (const float*)d_in[5];
    const float* t_b2 = (const float*)d_in[6];
    const float* t_a2 = (const float*)d_in[7];
    const float* t_w3 = (const float*)d_in[8];
    const float* t_b3 = (const float*)d_in[9];
    const float* g_w1 = (const float*)d_in[10];
    const float* g_b1 = (const float*)d_in[11];
    const float* g_a1 = (const float*)d_in[12];
    const float* g_w2 = (const float*)d_in[13];
    const float* g_b2 = (const float*)d_in[14];
    const float* g_a2 = (const float*)d_in[15];
    const float* g_w3 = (const float*)d_in[16];
    const float* g_b3 = (const float*)d_in[17];
    const float* j_w1 = (const float*)d_in[18];
    const float* j_b1 = (const float*)d_in[19];
    const float* j_a1 = (const float*)d_in[20];
    const float* j_w2 = (const float*)d_in[21];
    const float* j_b2 = (const float*)d_in[22];

    // workspace (ushort units): two NHWC f16 activation planes (16.8 MB each),
    // one single-batch ker plane (26.2 MB), repacked weights (~1 MB). ~61 MB.
    const size_t planeH  = (size_t)2 * HWSZ * 64;  // both batches
    const size_t halfH   = (size_t)HWSZ * 64;      // one batch
    ushort* bufA  = (ushort*)d_ws;
    ushort* bufB  = bufA + planeH;
    ushort* kerB  = bufB + planeH;                 // 65536*200
    ushort* wt_t1 = kerB + (size_t)HWSZ * 200;
    ushort* wt_t2 = wt_t1 + 102400;
    ushort* wt_g1 = wt_t2 + 102400;
    ushort* wt_g2 = wt_g1 + 102400;
    ushort* wt_j1 = wt_g2 + 102400;
    ushort* wt_j2 = wt_j1 + 36864;
    ushort* w3t   = wt_j2 + 36864;                 // [208][64]
    ushort* w3g   = w3t + 13312;
    ushort* bufC  = (ushort*)d_out;                // g2 NHWC f16 scratch

    repack_wf16<<<(64 * 64 * 25 + 255) / 256, 256, 0, stream>>>(t_w1, wt_t1, 25);
    repack_wf16<<<(64 * 64 * 25 + 255) / 256, 256, 0, stream>>>(t_w2, wt_t2, 25);
    repack_wf16<<<(64 * 64 * 25 + 255) / 256, 256, 0, stream>>>(g_w1, wt_g1, 25);
    repack_wf16<<<(64 * 64 * 25 + 255) / 256, 256, 0, stream>>>(g_w2, wt_g2, 25);
    repack_wf16<<<(64 * 64 * 9 + 255) / 256, 256, 0, stream>>>(j_w1, wt_j1, 9);
    repack_wf16<<<(64 * 64 * 9 + 255) / 256, 256, 0, stream>>>(j_w2, wt_j2, 9);
    cast_w3<<<(208 * 64 + 255) / 256, 256, 0, stream>>>(t_w3, w3t);
    cast_w3<<<(208 * 64 + 255) / 256, 256, 0, stream>>>(g_w3, w3g);

    dim3 cgrid(WDIM / 32, HDIM / 8, 2);
    dim3 blk(256);

    conv_mfma<5, true,  true,  false><<<cgrid, blk, 0, stream>>>(source,   wt_t1, t_b1, t_a1, nullptr, bufA);
    conv_mfma<5, false, true,  false><<<cgrid, blk, 0, stream>>>(bufA,     wt_t2, t_b2, t_a2, nullptr, bufB);
    conv_mfma<5, true,  true,  false><<<cgrid, blk, 0, stream>>>(guidance, wt_g1, g_b1, g_a1, nullptr, bufA);
    conv_mfma<5, false, true,  false><<<cgrid, blk, 0, stream>>>(bufA,     wt_g2, g_b2, g_a2, nullptr, bufC);

    // per-batch: bilateral kernel via MFMA, then 25-tap apply -> bufA (NHWC)
    dim3 agrid(HDIM / 16, WDIM / 16, 2);
    for (int b = 0; b < 2; ++b) {
        ker_mfma<<<dim3(HWSZ / 64), blk, 0, stream>>>(
            bufB + b * halfH, bufC + b * halfH, w3t, t_b3, w3g, g_b3, kerB);
        jbf_apply<<<agrid, blk, 0, stream>>>(
            kerB, source + (size_t)b * CDIM * HWSZ, bufA + b * halfH);
    }

    conv_mfma<3, false, true,  false><<<cgrid, blk, 0, stream>>>(bufA, wt_j1, j_b1, j_a1, nullptr, bufB);
    conv_mfma<3, false, false, true ><<<cgrid, blk, 0, stream>>>(bufB, wt_j2, j_b2, nullptr, source, d_out);
}

// Round 8
// 533.654 us; speedup vs baseline: 2.1288x; 1.2171x over previous
//
#include <hip/hip_runtime.h>

#define CDIM 64
#define HDIM 256
#define WDIM 256
#define HWSZ (HDIM * WDIM)
#define GNUM 8

typedef _Float16 f16;
typedef f16  f16x8  __attribute__((ext_vector_type(8)));
typedef float f32x4 __attribute__((ext_vector_type(4)));

static __device__ __forceinline__ ushort f16bits(float v) {
    f16 h = (f16)v;
    return __builtin_bit_cast(ushort, h);
}

// ---------------------------------------------------------------------------
// Repack OIHW f32 -> [tap][oc][ic-chunk XOR-swizzled] f16.
// LDS is written LINEARLY by global_load_lds, so the bank-conflict swizzle
// must be applied to the GLOBAL layout (rule: both-sides-or-neither).
// Fragment read uses chunk_sw = (ks*4+hi) ^ (oc&7)  ->  source chunk ks*4+hi.
// ---------------------------------------------------------------------------
__global__ __launch_bounds__(256) void repack_wf16(const float* __restrict__ w,
                                                   ushort* __restrict__ wt, int TAPS) {
    int idx = blockIdx.x * 256 + threadIdx.x;
    int total = 64 * 64 * TAPS;
    if (idx >= total) return;
    int tap = idx / 4096;
    int rem = idx - tap * 4096;
    int oc = rem >> 6, ic = rem & 63;
    int chunk = ic >> 3, j = ic & 7;
    int dst = tap * 4096 + oc * 64 + ((chunk ^ (oc & 7)) << 3) + j;
    wt[dst] = f16bits(w[(oc * 64 + ic) * TAPS + tap]);
}

// Cast 1x1 weights (200,64) OIHW f32 -> [208][64] f16, zero-padded (linear).
__global__ __launch_bounds__(256) void cast_w3(const float* __restrict__ w,
                                               ushort* __restrict__ wt) {
    int idx = blockIdx.x * 256 + threadIdx.x;
    if (idx >= 208 * 64) return;
    int oc = idx >> 6;
    wt[idx] = (oc < 200) ? f16bits(w[idx]) : (ushort)0;
}

// ---------------------------------------------------------------------------
// Implicit-GEMM conv via mfma_f32_16x16x32_f16.
// Block: 256 thr = 4 waves, tile 32x x 8y pixels, all 64 oc.
// sX: input tile staged once (XOR-swizzled 16B chunks by x&7).
// sW: DOUBLE-BUFFERED 8KB per-tap weights, staged via global_load_lds(16B)
//     from the pre-swizzled global array; stage(tap+1) issued BEFORE the
//     ds_read+MFMA of tap; ONE __syncthreads per tap (drains vmcnt+lgkm).
// ---------------------------------------------------------------------------
template <int KS, bool IN_F32_NCHW, bool PRELU, bool F32OUT>
__global__ __launch_bounds__(256, 2) void conv_mfma(
        const void* __restrict__ inp,
        const ushort* __restrict__ wt,     // f16 [tap][64][64] pre-swizzled
        const float* __restrict__ bias,
        const float* __restrict__ alpha,
        const float* __restrict__ resid,   // f32 NCHW (F32OUT only)
        void* __restrict__ outp) {
    constexpr int H    = KS / 2;
    constexpr int TAPS = KS * KS;
    constexpr int TX = 32, TY = 8;
    constexpr int IX = TX + 2 * H, IY = TY + 2 * H;
    constexpr int NP = IX * IY;

    __shared__ __align__(16) ushort sX[NP * 64];
    __shared__ __align__(16) ushort sW[2][4096];

    const int b    = blockIdx.z;
    const int bx   = blockIdx.x * TX;
    const int by   = blockIdx.y * TY;
    const int tid  = threadIdx.x;
    const int lane = tid & 63;
    const int wv   = tid >> 6;
    const int x0w  = (wv & 1) * 16;
    const int y0w  = (wv >> 1) * 4;
    const int lr   = lane & 15;
    const int hi   = lane >> 4;

    // async stage of one 8KB tap block: per wave 2 x (64 lanes x 16B)
    auto stageW = [&](int tap, int bufSel) {
        const ushort* gs = wt + (size_t)tap * 4096 + wv * 1024 + lane * 8;
        ushort* ls = &sW[bufSel][wv * 1024];
        __builtin_amdgcn_global_load_lds(
            (const __attribute__((address_space(1))) void*)gs,
            (__attribute__((address_space(3))) void*)ls, 16, 0, 0);
        __builtin_amdgcn_global_load_lds(
            (const __attribute__((address_space(1))) void*)(gs + 512),
            (__attribute__((address_space(3))) void*)(ls + 512), 16, 0, 0);
    };

    // ---- stage input tile (once) + first weight tap ----
    stageW(0, 0);
    if constexpr (IN_F32_NCHW) {
        const float* inf = (const float*)inp + (size_t)b * CDIM * HWSZ;
        for (int i = tid; i < CDIM * NP; i += 256) {
            int ch = i / NP, p = i - ch * NP;
            int iy = p / IX, ix = p - iy * IX;
            int gy = by - H + iy, gx = bx - H + ix;
            float v = 0.f;
            if (gy >= 0 && gy < HDIM && gx >= 0 && gx < WDIM)
                v = inf[ch * HWSZ + gy * WDIM + gx];
            int chunk = (ch >> 3) ^ (ix & 7);
            sX[p * 64 + chunk * 8 + (ch & 7)] = f16bits(v);
        }
    } else {
        const ushort* inh = (const ushort*)inp + (size_t)b * HWSZ * 64;
        for (int i = tid; i < NP * 8; i += 256) {
            int p = i >> 3, chunk = i & 7;
            int iy = p / IX, ix = p - iy * IX;
            int gy = by - H + iy, gx = bx - H + ix;
            uint4 v = make_uint4(0u, 0u, 0u, 0u);
            if (gy >= 0 && gy < HDIM && gx >= 0 && gx < WDIM)
                v = *(const uint4*)(inh + ((size_t)(gy * WDIM + gx)) * 64 + chunk * 8);
            *(uint4*)((char*)sX + p * 128 + ((chunk ^ (ix & 7)) << 4)) = v;
        }
    }
    __syncthreads();

    f32x4 acc[4][4] = {};

    for (int tap = 0; tap < TAPS; ++tap) {
        const int cur = tap & 1;
        if (tap + 1 < TAPS) stageW(tap + 1, cur ^ 1);
        const int dy = tap / KS, dx = tap - dy * KS;
#pragma unroll
        for (int ks = 0; ks < 2; ++ks) {
            f16x8 afr[4], bfr[4];
#pragma unroll
            for (int mt = 0; mt < 4; ++mt) {
                int iy = y0w + mt + dy;
                int ix = x0w + dx + lr;
                int chunk = (ks * 4 + hi) ^ (ix & 7);
                afr[mt] = *(const f16x8*)((const char*)sX + (iy * IX + ix) * 128 + (chunk << 4));
            }
#pragma unroll
            for (int nt = 0; nt < 4; ++nt) {
                int csw = (ks * 4 + hi) ^ (lr & 7);   // oc&7 == lr&7
                bfr[nt] = *(const f16x8*)((const char*)&sW[cur][0]
                             + (nt * 16 + lr) * 128 + (csw << 4));
            }
#pragma unroll
            for (int mt = 0; mt < 4; ++mt)
#pragma unroll
                for (int nt = 0; nt < 4; ++nt)
                    acc[mt][nt] = __builtin_amdgcn_mfma_f32_16x16x32_f16(
                        afr[mt], bfr[nt], acc[mt][nt], 0, 0, 0);
        }
        __syncthreads();   // drains vmcnt (next tap staged) + lgkm (reads done)
    }

    // ---- epilogue ----
    const float al = PRELU ? alpha[0] : 0.f;
#pragma unroll
    for (int nt = 0; nt < 4; ++nt) {
        const int oc = nt * 16 + lr;
        const float bs = bias[oc];
#pragma unroll
        for (int mt = 0; mt < 4; ++mt) {
            const int gy = by + y0w + mt;
            const int gxb = bx + x0w + hi * 4;
            if constexpr (!F32OUT) {
                ushort* o = (ushort*)outp + (size_t)b * HWSZ * 64;
#pragma unroll
                for (int r = 0; r < 4; ++r) {
                    float v = acc[mt][nt][r] + bs;
                    if constexpr (PRELU) v = (v >= 0.f) ? v : al * v;
                    o[((size_t)(gy * WDIM + gxb + r)) * 64 + oc] = f16bits(v);
                }
            } else {
                float* o = (float*)outp;
                size_t base = ((size_t)(b * CDIM + oc)) * HWSZ + gy * WDIM + gxb;
                float4 sv = *(const float4*)(resid + base);
                float4 ov;
                ov.x = acc[mt][nt][0] + bs + sv.x;
                ov.y = acc[mt][nt][1] + bs + sv.y;
                ov.z = acc[mt][nt][2] + bs + sv.z;
                ov.w = acc[mt][nt][3] + bs + sv.w;
                *(float4*)(o + base) = ov;
            }
        }
    }
}

// ---------------------------------------------------------------------------
// ker = (r2 . W3t + tb3) * (g2 . W3g + gb3)  per batch, via MFMA.
// M = pixels, N = 208 (200 used), K = 64. A-fragments direct from NHWC f16.
// ---------------------------------------------------------------------------
__global__ __launch_bounds__(256, 2) void ker_mfma(
        const ushort* __restrict__ r2,   // [65536][64] f16 (batch slice)
        const ushort* __restrict__ g2,
        const ushort* __restrict__ w3t,  // [208][64] f16 linear
        const float* __restrict__ tb3,
        const ushort* __restrict__ w3g,
        const float* __restrict__ gb3,
        ushort* __restrict__ ker) {      // [65536][200] f16
    const int tid  = threadIdx.x;
    const int lane = tid & 63;
    const int wv   = tid >> 6;
    const int lr   = lane & 15;
    const int hi   = lane >> 4;
    const int pixbase = blockIdx.x * 64 + wv * 16;

    f32x4 accr[13] = {}, accg[13] = {};
    const ushort* arb = r2 + (size_t)(pixbase + lr) * 64;
    const ushort* agb = g2 + (size_t)(pixbase + lr) * 64;

#pragma unroll
    for (int ks = 0; ks < 2; ++ks) {
        f16x8 ar = *(const f16x8*)(arb + ks * 32 + hi * 8);
        f16x8 ag = *(const f16x8*)(agb + ks * 32 + hi * 8);
#pragma unroll
        for (int nt = 0; nt < 13; ++nt) {
            f16x8 bt = *(const f16x8*)(w3t + (nt * 16 + lr) * 64 + ks * 32 + hi * 8);
            f16x8 bg = *(const f16x8*)(w3g + (nt * 16 + lr) * 64 + ks * 32 + hi * 8);
            accr[nt] = __builtin_amdgcn_mfma_f32_16x16x32_f16(ar, bt, accr[nt], 0, 0, 0);
            accg[nt] = __builtin_amdgcn_mfma_f32_16x16x32_f16(ag, bg, accg[nt], 0, 0, 0);
        }
    }

#pragma unroll
    for (int nt = 0; nt < 13; ++nt) {
        const int oc = nt * 16 + lr;
        const bool ok = (oc < 200);
        const float bt = ok ? tb3[oc] : 0.f;
        const float bg = ok ? gb3[oc] : 0.f;
#pragma unroll
        for (int r = 0; r < 4; ++r) {
            const int p = pixbase + hi * 4 + r;
            float kv = (accr[nt][r] + bt) * (accg[nt][r] + bg);
            if (ok) ker[(size_t)p * 200 + oc] = f16bits(kv);
        }
    }
}

// ---------------------------------------------------------------------------
// 25-tap grouped apply (validated round 7): pixel-major LDS, 4 groups/block.
// ---------------------------------------------------------------------------
__global__ __launch_bounds__(256) void jbf_apply(
        const ushort* __restrict__ ker,  // [65536][200] f16
        const float* __restrict__ src,   // f32 NCHW batch slice
        ushort* __restrict__ out) {      // f16 NHWC batch slice
    __shared__ __align__(16) float sSrc[20 * 20 * 8];

    const int g0  = blockIdx.z * 4;
    const int tx0 = blockIdx.x * 16;
    const int ty0 = blockIdx.y * 16;
    const int tid = threadIdx.x;
    const int lx  = tid & 15;
    const int ly  = tid >> 4;
    const int pix = (ty0 + ly) * WDIM + (tx0 + lx);

    for (int gi = 0; gi < 4; ++gi) {
        const int g = g0 + gi;
        __syncthreads();
        for (int i = tid; i < 3200; i += 256) {
            int c   = i / 400;
            int rem = i - c * 400;
            int yy  = rem / 20, xx = rem - yy * 20;
            int gy  = ty0 - 2 + yy, gx = tx0 - 2 + xx;
            float v = 0.f;
            if (gy >= 0 && gy < HDIM && gx >= 0 && gx < WDIM)
                v = src[(size_t)(g * 8 + c) * HWSZ + gy * WDIM + gx];
            sSrc[(yy * 20 + xx) * 8 + c] = v;
        }
        __syncthreads();

        float kt[25];
        const ushort* kp = ker + (size_t)pix * 200 + g * 25;
#pragma unroll
        for (int t = 0; t < 25; ++t)
            kt[t] = (float)(*(const f16*)(kp + t));

        float a8[8] = {};
#pragma unroll
        for (int t = 0; t < 25; ++t) {
            const int dy = t / 5, dx = t - dy * 5;
            const float* sp = &sSrc[((ly + dy) * 20 + (lx + dx)) * 8];
            f32x4 v0 = *(const f32x4*)sp;
            f32x4 v1 = *(const f32x4*)(sp + 4);
#pragma unroll
            for (int c = 0; c < 4; ++c) {
                a8[c]     = fmaf(kt[t], v0[c], a8[c]);
                a8[c + 4] = fmaf(kt[t], v1[c], a8[c + 4]);
            }
        }

        f16x8 h;
#pragma unroll
        for (int c = 0; c < 8; ++c) h[c] = (f16)a8[c];
        *(uint4*)(out + (size_t)pix * 64 + g * 8) = __builtin_bit_cast(uint4, h);
    }
}

// ---------------------------------------------------------------------------
extern "C" void kernel_launch(void* const* d_in, const int* in_sizes, int n_in,
                              void* d_out, int out_size, void* d_ws, size_t ws_size,
                              hipStream_t stream) {
    const float* source   = (const float*)d_in[0];
    const float* guidance = (const float*)d_in[1];
    const float* t_w1 = (const float*)d_in[2];
    const float* t_b1 = (const float*)d_in[3];
    const float* t_a1 = (const float*)d_in[4];
    const float* t_w2 = (const float*)d_in[5];
    const float* t_b2 = (const float*)d_in[6];
    const float* t_a2 = (const float*)d_in[7];
    const float* t_w3 = (const float*)d_in[8];
    const float* t_b3 = (const float*)d_in[9];
    const float* g_w1 = (const float*)d_in[10];
    const float* g_b1 = (const float*)d_in[11];
    const float* g_a1 = (const float*)d_in[12];
    const float* g_w2 = (const float*)d_in[13];
    const float* g_b2 = (const float*)d_in[14];
    const float* g_a2 = (const float*)d_in[15];
    const float* g_w3 = (const float*)d_in[16];
    const float* g_b3 = (const float*)d_in[17];
    const float* j_w1 = (const float*)d_in[18];
    const float* j_b1 = (const float*)d_in[19];
    const float* j_a1 = (const float*)d_in[20];
    const float* j_w2 = (const float*)d_in[21];
    const float* j_b2 = (const float*)d_in[22];

    const size_t planeH  = (size_t)2 * HWSZ * 64;  // both batches
    const size_t halfH   = (size_t)HWSZ * 64;      // one batch
    ushort* bufA  = (ushort*)d_ws;
    ushort* bufB  = bufA + planeH;
    ushort* kerB  = bufB + planeH;                 // 65536*200
    ushort* wt_t1 = kerB + (size_t)HWSZ * 200;
    ushort* wt_t2 = wt_t1 + 102400;
    ushort* wt_g1 = wt_t2 + 102400;
    ushort* wt_g2 = wt_g1 + 102400;
    ushort* wt_j1 = wt_g2 + 102400;
    ushort* wt_j2 = wt_j1 + 36864;
    ushort* w3t   = wt_j2 + 36864;                 // [208][64]
    ushort* w3g   = w3t + 13312;
    ushort* bufC  = (ushort*)d_out;                // g2 NHWC f16 scratch

    repack_wf16<<<(64 * 64 * 25 + 255) / 256, 256, 0, stream>>>(t_w1, wt_t1, 25);
    repack_wf16<<<(64 * 64 * 25 + 255) / 256, 256, 0, stream>>>(t_w2, wt_t2, 25);
    repack_wf16<<<(64 * 64 * 25 + 255) / 256, 256, 0, stream>>>(g_w1, wt_g1, 25);
    repack_wf16<<<(64 * 64 * 25 + 255) / 256, 256, 0, stream>>>(g_w2, wt_g2, 25);
    repack_wf16<<<(64 * 64 * 9 + 255) / 256, 256, 0, stream>>>(j_w1, wt_j1, 9);
    repack_wf16<<<(64 * 64 * 9 + 255) / 256, 256, 0, stream>>>(j_w2, wt_j2, 9);
    cast_w3<<<(208 * 64 + 255) / 256, 256, 0, stream>>>(t_w3, w3t);
    cast_w3<<<(208 * 64 + 255) / 256, 256, 0, stream>>>(g_w3, w3g);

    dim3 cgrid(WDIM / 32, HDIM / 8, 2);
    dim3 blk(256);

    conv_mfma<5, true,  true,  false><<<cgrid, blk, 0, stream>>>(source,   wt_t1, t_b1, t_a1, nullptr, bufA);
    conv_mfma<5, false, true,  false><<<cgrid, blk, 0, stream>>>(bufA,     wt_t2, t_b2, t_a2, nullptr, bufB);
    conv_mfma<5, true,  true,  false><<<cgrid, blk, 0, stream>>>(guidance, wt_g1, g_b1, g_a1, nullptr, bufA);
    conv_mfma<5, false, true,  false><<<cgrid, blk, 0, stream>>>(bufA,     wt_g2, g_b2, g_a2, nullptr, bufC);

    dim3 agrid(HDIM / 16, WDIM / 16, 2);
    for (int b = 0; b < 2; ++b) {
        ker_mfma<<<dim3(HWSZ / 64), blk, 0, stream>>>(
            bufB + b * halfH, bufC + b * halfH, w3t, t_b3, w3g, g_b3, kerB);
        jbf_apply<<<agrid, blk, 0, stream>>>(
            kerB, source + (size_t)b * CDIM * HWSZ, bufA + b * halfH);
    }

    conv_mfma<3, false, true,  false><<<cgrid, blk, 0, stream>>>(bufA, wt_j1, j_b1, j_a1, nullptr, bufB);
    conv_mfma<3, false, false, true ><<<cgrid, blk, 0, stream>>>(bufB, wt_j2, j_b2, nullptr, source, d_out);
}